// Round 4
// baseline (144.096 us; speedup 1.0000x reference)
//
#include <hip/hip_runtime.h>
#include <hip/hip_bf16.h>

#define B_SZ 8
#define L_SEQ 144
#define NTOK 1152
#define D_MODEL 256
#define D_INNER 512
#define D_STATE 64
#define DT_RANK 4

typedef __attribute__((ext_vector_type(8))) short bf16x8;   // MFMA A/B frag (4 VGPRs)
typedef __attribute__((ext_vector_type(4))) float f32x4;    // MFMA C/D frag
typedef __attribute__((ext_vector_type(4))) short short4v;

__device__ __forceinline__ unsigned short bf16_rn(float f) {
    unsigned u = __float_as_uint(f);
    u += 0x7FFF + ((u >> 16) & 1);           // round-to-nearest-even
    return (unsigned short)(u >> 16);
}
__device__ __forceinline__ float bf16_f(unsigned short h) {
    return __uint_as_float(((unsigned)h) << 16);
}
// split f32 -> (hi bf16, lo bf16) packed in one u32: lo<<16 | hi
__device__ __forceinline__ unsigned packsplit(float f) {
    const unsigned short h = bf16_rn(f);
    const unsigned short l = bf16_rn(f - bf16_f(h));
    return (unsigned)h | ((unsigned)l << 16);
}

// ---------------------------------------------------------------------------
// bf16x3 MFMA GEMM: C[M,N] = A[M,K] . B[N,K]^T, fp32 in/out, ~fp32 accuracy.
// 64x64 block tile, 4 waves, each wave 32x32 (2x2 MFMA 16x16x32 tiles).
// APACK: A rows are u32 packsplit() pairs (pre-transposed activations).
//        else A is f32 [m][k], split during staging (weights, x).
// B is always f32 [n][k], split during staging. GN: guard n < N.
// LDS: 4 tiles [64][LP] bf16, LP=40 (80 B pitch: b128-aligned, <=2-way banks).
// ---------------------------------------------------------------------------
#define LP 40

template<bool APACK, bool GN>
__global__ __launch_bounds__(256) void gemm_mfma(const void* __restrict__ Aptr,
                                                 const float* __restrict__ Bptr,
                                                 float* __restrict__ C,
                                                 const int N, const int K,
                                                 const int lda, const int ldb,
                                                 const int ldc) {
    __shared__ short Ah[64 * LP], Al[64 * LP], Bh[64 * LP], Bl[64 * LP];
    const float* Af = (const float*)Aptr;
    const unsigned* Au = (const unsigned*)Aptr;
    const int tid = threadIdx.x;
    const int m0 = blockIdx.y * 64;
    const int n0 = blockIdx.x * 64;
    const int w = tid >> 6, l = tid & 63;
    const int lm = l & 15, lq = l >> 4;
    const int m0w = (w >> 1) * 32, n0w = (w & 1) * 32;
    f32x4 acc[2][2] = {};

    for (int k0 = 0; k0 < K; k0 += 32) {
        unsigned short ha[2][4], la[2][4], hb[2][4], lb[2][4];
#pragma unroll
        for (int p = 0; p < 2; ++p) {                 // 512 float4-slots / 256 thr
            const int i = tid + 256 * p;
            const int r = i >> 3, c = (i & 7) * 4;    // r: 0..63 row, c: k-quad
            if (APACK) {
                const uint4 v = *(const uint4*)(Au + (size_t)(m0 + r) * lda + k0 + c);
                ha[p][0] = v.x & 0xFFFF; la[p][0] = v.x >> 16;
                ha[p][1] = v.y & 0xFFFF; la[p][1] = v.y >> 16;
                ha[p][2] = v.z & 0xFFFF; la[p][2] = v.z >> 16;
                ha[p][3] = v.w & 0xFFFF; la[p][3] = v.w >> 16;
            } else {
                const float4 v = *(const float4*)(Af + (size_t)(m0 + r) * lda + k0 + c);
                ha[p][0] = bf16_rn(v.x); la[p][0] = bf16_rn(v.x - bf16_f(ha[p][0]));
                ha[p][1] = bf16_rn(v.y); la[p][1] = bf16_rn(v.y - bf16_f(ha[p][1]));
                ha[p][2] = bf16_rn(v.z); la[p][2] = bf16_rn(v.z - bf16_f(ha[p][2]));
                ha[p][3] = bf16_rn(v.w); la[p][3] = bf16_rn(v.w - bf16_f(ha[p][3]));
            }
            float4 bv = make_float4(0.f, 0.f, 0.f, 0.f);
            if (!GN || (n0 + r) < N)
                bv = *(const float4*)(Bptr + (size_t)(n0 + r) * ldb + k0 + c);
            hb[p][0] = bf16_rn(bv.x); lb[p][0] = bf16_rn(bv.x - bf16_f(hb[p][0]));
            hb[p][1] = bf16_rn(bv.y); lb[p][1] = bf16_rn(bv.y - bf16_f(hb[p][1]));
            hb[p][2] = bf16_rn(bv.z); lb[p][2] = bf16_rn(bv.z - bf16_f(hb[p][2]));
            hb[p][3] = bf16_rn(bv.w); lb[p][3] = bf16_rn(bv.w - bf16_f(hb[p][3]));
        }
        __syncthreads();                               // prev chunk frags consumed
#pragma unroll
        for (int p = 0; p < 2; ++p) {
            const int i = tid + 256 * p;
            const int r = i >> 3, c = (i & 7) * 4;
            const int o = r * LP + c;
            short4v v;
            v = (short4v){(short)ha[p][0], (short)ha[p][1], (short)ha[p][2], (short)ha[p][3]};
            *(short4v*)&Ah[o] = v;
            v = (short4v){(short)la[p][0], (short)la[p][1], (short)la[p][2], (short)la[p][3]};
            *(short4v*)&Al[o] = v;
            v = (short4v){(short)hb[p][0], (short)hb[p][1], (short)hb[p][2], (short)hb[p][3]};
            *(short4v*)&Bh[o] = v;
            v = (short4v){(short)lb[p][0], (short)lb[p][1], (short)lb[p][2], (short)lb[p][3]};
            *(short4v*)&Bl[o] = v;
        }
        __syncthreads();
        bf16x8 fah[2], fal[2], fbh[2], fbl[2];
#pragma unroll
        for (int t = 0; t < 2; ++t) {
            // A-frag: lane holds A[m=lane&15][k=(lane>>4)*8 + j]; B symmetric
            const int ao = (m0w + t * 16 + lm) * LP + lq * 8;
            fah[t] = *(const bf16x8*)&Ah[ao];
            fal[t] = *(const bf16x8*)&Al[ao];
            const int bo = (n0w + t * 16 + lm) * LP + lq * 8;
            fbh[t] = *(const bf16x8*)&Bh[bo];
            fbl[t] = *(const bf16x8*)&Bl[bo];
        }
#pragma unroll
        for (int mt = 0; mt < 2; ++mt)
#pragma unroll
            for (int nt = 0; nt < 2; ++nt) {
                acc[mt][nt] = __builtin_amdgcn_mfma_f32_16x16x32_bf16(
                    fal[mt], fbh[nt], acc[mt][nt], 0, 0, 0);
                acc[mt][nt] = __builtin_amdgcn_mfma_f32_16x16x32_bf16(
                    fah[mt], fbl[nt], acc[mt][nt], 0, 0, 0);
                acc[mt][nt] = __builtin_amdgcn_mfma_f32_16x16x32_bf16(
                    fah[mt], fbh[nt], acc[mt][nt], 0, 0, 0);
            }
    }
    // C/D layout: col = lane&15 (n), row = (lane>>4)*4 + reg (m)
#pragma unroll
    for (int mt = 0; mt < 2; ++mt) {
        const int gm = m0 + m0w + mt * 16 + lq * 4;
#pragma unroll
        for (int nt = 0; nt < 2; ++nt) {
            const int gn = n0 + n0w + nt * 16 + lm;
            if (!GN || gn < N) {
#pragma unroll
                for (int r = 0; r < 4; ++r)
                    C[(size_t)(gm + r) * ldc + gn] = acc[mt][nt][r];
            }
        }
    }
}

// ---------------------------------------------------------------------------
// Transpose [512][1152] f32 -> [1152][512] u32 (bf16 hi|lo packsplit).
// 64x64 LDS tile, pitch 65 (scalar u32 ops, <=2-way banks), coalesced IO.
// ---------------------------------------------------------------------------
__global__ __launch_bounds__(256) void transpack_k(const float* __restrict__ in,
                                                   unsigned* __restrict__ out) {
    __shared__ unsigned T[64][65];
    const int t0 = blockIdx.x * 64, d0 = blockIdx.y * 64;
    const int a = threadIdx.x & 15, g = threadIdx.x >> 4;
#pragma unroll
    for (int p = 0; p < 4; ++p) {
        const int d = g + 16 * p;
        const float4 v = *(const float4*)(in + (size_t)(d0 + d) * NTOK + t0 + a * 4);
        T[d][a * 4 + 0] = packsplit(v.x);
        T[d][a * 4 + 1] = packsplit(v.y);
        T[d][a * 4 + 2] = packsplit(v.z);
        T[d][a * 4 + 3] = packsplit(v.w);
    }
    __syncthreads();
#pragma unroll
    for (int p = 0; p < 4; ++p) {
        const int tt = g + 16 * p;
        uint4 o;
        o.x = T[a * 4 + 0][tt];
        o.y = T[a * 4 + 1][tt];
        o.z = T[a * 4 + 2][tt];
        o.w = T[a * 4 + 3][tt];
        *(uint4*)(out + (size_t)(t0 + tt) * D_INNER + d0 + a * 4) = o;
    }
}

// ---------------------------------------------------------------------------
// Depthwise conv(4) + SiLU on t-major layout (unchanged, passing)
// ---------------------------------------------------------------------------
__global__ __launch_bounds__(128) void conv_k(const float* __restrict__ xzT,
                                              const float* __restrict__ cw,
                                              const float* __restrict__ cb,
                                              float* __restrict__ ixT) {
    const int tok = blockIdx.x * 128 + threadIdx.x;
    const int d = blockIdx.y;
    const int b = tok / L_SEQ;
    const int t = tok - b * L_SEQ;
    const float* row = xzT + (size_t)d * NTOK + tok;
    const float4 w = *(const float4*)(cw + d * 4);
    float s = cb[d];
    if (t >= 2) s = fmaf(w.x, row[-2], s);
    if (t >= 1) s = fmaf(w.y, row[-1], s);
    s = fmaf(w.z, row[0], s);
    if (t < L_SEQ - 1) s = fmaf(w.w, row[1], s);
    ixT[(size_t)d * NTOK + tok] = s * __builtin_amdgcn_rcpf(1.f + __expf(-s));
}

// ---------------------------------------------------------------------------
// Fused aux + selective scan (unchanged, passing). One wave per (b,d).
// ---------------------------------------------------------------------------
template<int CNT>
__device__ __forceinline__ void scan_chunk(const float* __restrict__ dBC,
                                           const float* __restrict__ xzT,
                                           const float* __restrict__ ixT,
                                           float* __restrict__ gT,
                                           float4* __restrict__ aux_w,
                                           float (*__restrict__ Pw)[65],
                                           const int d, const int base, const int t0,
                                           const float An2, const float4 wdt,
                                           const float bdt, const float dpv,
                                           const int lane, float& h) {
    if (lane < CNT) {
        const int tok = base + t0 + lane;
        const float4 dt4 = *(const float4*)(dBC + (size_t)tok * 132);
        float s = fmaf(dt4.x, wdt.x, bdt);
        s = fmaf(dt4.y, wdt.y, s);
        s = fmaf(dt4.z, wdt.z, s);
        s = fmaf(dt4.w, wdt.w, s);
        const float delta = fmaxf(s, 0.f) + __logf(1.f + __expf(-fabsf(s)));
        const float ixv = ixT[(size_t)d * NTOK + tok];
        const float zv  = xzT[(size_t)(D_INNER + d) * NTOK + tok];
        const float sz  = zv * __builtin_amdgcn_rcpf(1.f + __expf(-zv));
        aux_w[lane] = make_float4(delta, delta * ixv, dpv * ixv, sz);
    }
#pragma unroll 8
    for (int i = 0; i < CNT; ++i) {
        const size_t rb = (size_t)(base + t0 + i) * 132;
        const float Bv = dBC[rb + DT_RANK + lane];
        const float Cv = dBC[rb + DT_RANK + D_STATE + lane];
        const float4 a4 = aux_w[i];
        const float dA = __builtin_amdgcn_exp2f(a4.x * An2);
        h = fmaf(dA, h, a4.y * Bv);
        Pw[i][lane] = h * Cv;
    }
    const int tl = lane & 31, hf = lane >> 5;
    float s2 = 0.f;
    if (tl < CNT) {
#pragma unroll
        for (int j = 0; j < 32; ++j) s2 += Pw[tl][hf * 32 + j];
    }
    s2 += __shfl_xor(s2, 32, 64);
    if (hf == 0 && tl < CNT) {
        const float4 a4 = aux_w[tl];
        gT[(size_t)d * NTOK + base + t0 + tl] = (s2 + a4.z) * a4.w;
    }
}

__global__ __launch_bounds__(256) void scan_k(const float* __restrict__ dBC,
                                              const float* __restrict__ xzT,
                                              const float* __restrict__ ixT,
                                              const float* __restrict__ W_dt,
                                              const float* __restrict__ b_dt,
                                              const float* __restrict__ A_log,
                                              const float* __restrict__ Dp,
                                              float* __restrict__ gT) {
    __shared__ float4 aux_s[4][32];
    __shared__ float P[4][32][65];
    const int w = threadIdx.x >> 6, lane = threadIdx.x & 63;
    const int b = blockIdx.x >> 7, dg = blockIdx.x & 127;
    const int d = (dg << 2) | w;
    const int base = b * L_SEQ;
    const float An2 = -__expf(A_log[(d << 6) + lane]) * 1.44269504088896f;
    const float4 wdt = *(const float4*)(W_dt + (d << 2));
    const float bdt = b_dt[d], dpv = Dp[d];
    float h = 0.f;
    scan_chunk<32>(dBC, xzT, ixT, gT, aux_s[w], P[w], d, base, 0,  An2, wdt, bdt, dpv, lane, h);
    scan_chunk<32>(dBC, xzT, ixT, gT, aux_s[w], P[w], d, base, 32, An2, wdt, bdt, dpv, lane, h);
    scan_chunk<32>(dBC, xzT, ixT, gT, aux_s[w], P[w], d, base, 64, An2, wdt, bdt, dpv, lane, h);
    scan_chunk<32>(dBC, xzT, ixT, gT, aux_s[w], P[w], d, base, 96, An2, wdt, bdt, dpv, lane, h);
    scan_chunk<16>(dBC, xzT, ixT, gT, aux_s[w], P[w], d, base, 128, An2, wdt, bdt, dpv, lane, h);
}

// ---------------------------------------------------------------------------
extern "C" void kernel_launch(void* const* d_in, const int* in_sizes, int n_in,
                              void* d_out, int out_size, void* d_ws, size_t ws_size,
                              hipStream_t stream) {
    const float* x      = (const float*)d_in[0];
    // d_in[1] = lastin (unused: reference starts from h0 = 0)
    const float* W_in   = (const float*)d_in[2];
    const float* conv_w = (const float*)d_in[3];
    const float* conv_b = (const float*)d_in[4];
    const float* W_x    = (const float*)d_in[5];
    const float* W_dt   = (const float*)d_in[6];
    const float* b_dt   = (const float*)d_in[7];
    const float* A_log  = (const float*)d_in[8];
    const float* Dp     = (const float*)d_in[9];
    const float* W_out  = (const float*)d_in[10];
    float* out = (float*)d_out;

    float* ws  = (float*)d_ws;
    float* xzT = ws;                      // [1024][1152] f32
    float* ixT = xzT + 1179648;           // [512][1152]  f32
    float* dBC = ixT + 589824;            // [1152][132]  f32
    float* gT  = dBC + 152064;            // [512][1152]  f32
    unsigned* ixM = (unsigned*)(gT + 589824);   // [1152][512] packed bf16 pair
    unsigned* gM  = ixM + 589824;               // [1152][512] packed bf16 pair

    // 1) xzT[e][tok] = W_in[e][:] . x[tok][:]    M=1024 N=1152 K=256
    gemm_mfma<false, false><<<dim3(18, 16), 256, 0, stream>>>(
        W_in, x, xzT, NTOK, D_MODEL, D_MODEL, D_MODEL, NTOK);
    // 2) depthwise conv + silu -> ixT[d][tok]
    conv_k<<<dim3(9, D_INNER), 128, 0, stream>>>(xzT, conv_w, conv_b, ixT);
    // 3) ixT -> ixM [tok][d] packed
    transpack_k<<<dim3(18, 8), 256, 0, stream>>>(ixT, ixM);
    // 4) dBC[tok][e] = ix[tok][:] . W_x[e][:]    M=1152 N=132 K=512
    gemm_mfma<true, true><<<dim3(3, 18), 256, 0, stream>>>(
        ixM, W_x, dBC, 132, D_INNER, D_INNER, D_INNER, 132);
    // 5) fused aux + selective scan -> gT[d][tok]
    scan_k<<<dim3(B_SZ * 128), 256, 0, stream>>>(dBC, xzT, ixT, W_dt, b_dt, A_log, Dp, gT);
    // 6) gT -> gM [tok][d] packed
    transpack_k<<<dim3(18, 8), 256, 0, stream>>>(gT, gM);
    // 7) out[tok][e] = g[tok][:] . W_out[e][:]   M=1152 N=256 K=512
    gemm_mfma<true, false><<<dim3(4, 18), 256, 0, stream>>>(
        gM, W_out, out, D_MODEL, D_INNER, D_INNER, D_INNER, D_MODEL);
}